// Round 3
// baseline (303.769 us; speedup 1.0000x reference)
//
#include <hip/hip_runtime.h>

// LSTM (B=4096, T=512, IN=4, H=50) + final FC, MFMA formulation v3.
// gates[200x16] = Wcat[200x64] @ [h;x][64x16] per step via mfma 16x16x32 bf16.
// k-axis PERMUTED: unit u=4T+lg stored at k=16*lg+T (T=tile 0..12), x comp a
// at k=16*a+13. This makes the per-step h ds_write_u16 pattern dword-disjoint
// (R2 had 2-way same-dword write conflicts = 90 cyc/block-step).
// Waves 0-4: tiles {w, w+5}; waves 5,6: {w+5}; wave 7: tile 12 + x duty.

#define HID  50
#define NROW 200
#define TT   512
#define NIN  4
#define BT   16
#define KD   72      // shorts per row (144 B = odd*16): k 0..63 live
#define NW   8

typedef float f32x4 __attribute__((ext_vector_type(4)));
typedef short s16x8 __attribute__((ext_vector_type(8)));

__device__ __forceinline__ unsigned short f2bf(float f) {
    unsigned u = __builtin_bit_cast(unsigned, f);
    return (unsigned short)((u + 0x7FFF + ((u >> 16) & 1)) >> 16);
}
__device__ __forceinline__ float fast_sigmoid(float v) {
    float e = __builtin_amdgcn_exp2f(v * -1.442695040888963f);
    return __builtin_amdgcn_rcpf(1.0f + e);
}
__device__ __forceinline__ float fast_tanh(float v) {
    float e = __builtin_amdgcn_exp2f(v * -2.885390081777927f);
    return 2.0f * __builtin_amdgcn_rcpf(1.0f + e) - 1.0f;
}

// weight for interleaved A-row rowp (=4u+g) at permuted k-position k
__device__ __forceinline__ float wval(const float* W_hh, const float* W_ih,
                                      int rowp, int k) {
    if (rowp >= NROW) return 0.0f;
    const int ur = rowp >> 2, g = rowp & 3;
    const int a = k >> 4, b = k & 15;
    if (b <= 12) { const int u = 4 * b + a;
                   return (u < HID) ? W_hh[(g * HID + ur) * HID + u] : 0.0f; }
    if (b == 13) return W_ih[(g * HID + ur) * NIN + a];
    return 0.0f;
}

__global__ __launch_bounds__(64 * NW, 2)
void lstm_mfma3(const float* __restrict__ x,     // [B,T,4]
                const float* __restrict__ W_ih,  // [200,4]
                const float* __restrict__ W_hh,  // [200,50]
                const float* __restrict__ b_ih,  // [200]
                const float* __restrict__ b_hh,  // [200]
                const float* __restrict__ W_fc,  // [1,50]
                const float* __restrict__ b_fc,  // [1]
                float* __restrict__ out)         // [B,1]
{
    __shared__ __align__(16) unsigned short buf[2][BT][KD];
    __shared__ float red[BT];

    const int tid = threadIdx.x;
    const int w   = tid >> 6;
    const int l   = tid & 63;
    const int lr  = l & 15;          // batch col / A row-in-tile
    const int lg  = l >> 4;          // k-group / D row-group
    const int b0  = blockIdx.x * BT;

    for (int i = tid; i < 2 * BT * KD; i += 64 * NW)
        ((unsigned short*)buf)[i] = 0;
    if (tid < BT) red[tid] = 0.0f;

    const bool two = (w < 5);
    const int  T0  = two ? w : (w + 5);   // waves 5,6,7 -> tiles 10,11,12
    const int  T1  = w + 5;               // valid only when two

    // ---- preload A fragments, bias, W_fc (once) ----
    s16x8 af0[2], af1[2];
    f32x4 bias0, bias1 = {0.f, 0.f, 0.f, 0.f};
    float wfc0 = 0.0f, wfc1 = 0.0f;
    {
        const int rowp = 16 * T0 + lr;
#pragma unroll
        for (int kh = 0; kh < 2; ++kh) {
            s16x8 f;
#pragma unroll
            for (int j = 0; j < 8; ++j)
                f[j] = (short)f2bf(wval(W_hh, W_ih, rowp, 32 * kh + 8 * lg + j));
            af0[kh] = f;
        }
#pragma unroll
        for (int r = 0; r < 4; ++r) {
            const int rr = 16 * T0 + 4 * lg + r;
            bias0[r] = (rr < NROW) ? (b_ih[(rr & 3) * HID + (rr >> 2)] +
                                      b_hh[(rr & 3) * HID + (rr >> 2)]) : 0.0f;
        }
        const int u = 4 * T0 + lg;
        wfc0 = (u < HID) ? W_fc[u] : 0.0f;
    }
    if (two) {
        const int rowp = 16 * T1 + lr;
#pragma unroll
        for (int kh = 0; kh < 2; ++kh) {
            s16x8 f;
#pragma unroll
            for (int j = 0; j < 8; ++j)
                f[j] = (short)f2bf(wval(W_hh, W_ih, rowp, 32 * kh + 8 * lg + j));
            af1[kh] = f;
        }
#pragma unroll
        for (int r = 0; r < 4; ++r) {
            const int rr = 16 * T1 + 4 * lg + r;
            bias1[r] = (rr < NROW) ? (b_ih[(rr & 3) * HID + (rr >> 2)] +
                                      b_hh[(rr & 3) * HID + (rr >> 2)]) : 0.0f;
        }
        const int u = 4 * T1 + lg;
        wfc1 = (u < HID) ? W_fc[u] : 0.0f;
    }

    // wave 7: whole-wave x duty — lane (lr,lg) handles x[b0+lr][t][lg]
    const float* xg = x + ((size_t)(b0 + lr) * TT) * NIN + lg;
    if (w == 7) buf[0][lr][16 * lg + 13] = f2bf(xg[0]);
    __syncthreads();

    float c0 = 0.f, h0 = 0.f, c1 = 0.f, h1 = 0.f;

    for (int t = 0; t < TT; ++t) {
        const int p = t & 1;

        float xv = 0.0f;
        const bool xload = (w == 7) && (t + 1 < TT);   // wave-uniform
        if (xload) xv = xg[(size_t)(t + 1) * NIN];

        const s16x8 bf0v = *(const s16x8*)&buf[p][lr][8 * lg];        // k 0..31
        const s16x8 bf1v = *(const s16x8*)&buf[p][lr][32 + 8 * lg];   // k 32..63

        f32x4 a0 = bias0;
        a0 = __builtin_amdgcn_mfma_f32_16x16x32_bf16(af0[0], bf0v, a0, 0, 0, 0);
        a0 = __builtin_amdgcn_mfma_f32_16x16x32_bf16(af0[1], bf1v, a0, 0, 0, 0);
        f32x4 a1;
        if (two) {
            a1 = bias1;
            a1 = __builtin_amdgcn_mfma_f32_16x16x32_bf16(af1[0], bf0v, a1, 0, 0, 0);
            a1 = __builtin_amdgcn_mfma_f32_16x16x32_bf16(af1[1], bf1v, a1, 0, 0, 0);
        }

        if (xload) buf[p ^ 1][lr][16 * lg + 13] = f2bf(xv);

        {
            const float gi = fast_sigmoid(a0[0]);
            const float gf = fast_sigmoid(a0[1]);
            const float gg = fast_tanh(a0[2]);
            const float go = fast_sigmoid(a0[3]);
            c0 = gf * c0 + gi * gg;
            h0 = go * fast_tanh(c0);
        }
        if (two) {
            const float gi = fast_sigmoid(a1[0]);
            const float gf = fast_sigmoid(a1[1]);
            const float gg = fast_tanh(a1[2]);
            const float go = fast_sigmoid(a1[3]);
            c1 = gf * c1 + gi * gg;
            h1 = go * fast_tanh(c1);
            unsigned pk;
            asm("v_cvt_pk_bf16_f32 %0, %1, %2" : "=v"(pk) : "v"(h0), "v"(h1));
            buf[p ^ 1][lr][16 * lg + T0] = (unsigned short)pk;
            buf[p ^ 1][lr][16 * lg + T1] = (unsigned short)(pk >> 16);
        } else {
            buf[p ^ 1][lr][16 * lg + T0] = f2bf(h0);
        }
        __syncthreads();
    }

    // ---- FC epilogue ----
    float partial = wfc0 * h0 + wfc1 * h1;   // wfc1=h1=0 for single-tile waves
    partial += __shfl_down(partial, 32);
    partial += __shfl_down(partial, 16);
    if (l < 16) atomicAdd(&red[l], partial);
    __syncthreads();
    if (tid < BT) out[b0 + tid] = red[tid] + b_fc[0];
}

extern "C" void kernel_launch(void* const* d_in, const int* in_sizes, int n_in,
                              void* d_out, int out_size, void* d_ws, size_t ws_size,
                              hipStream_t stream) {
    const float* x    = (const float*)d_in[0];
    const float* W_ih = (const float*)d_in[1];
    const float* W_hh = (const float*)d_in[2];
    const float* b_ih = (const float*)d_in[3];
    const float* b_hh = (const float*)d_in[4];
    const float* W_fc = (const float*)d_in[5];
    const float* b_fc = (const float*)d_in[6];
    float* out        = (float*)d_out;

    const int B = in_sizes[0] / (TT * NIN);   // 4096
    lstm_mfma3<<<B / BT, 64 * NW, 0, stream>>>(x, W_ih, W_hh, b_ih, b_hh, W_fc, b_fc, out);
}